// Round 1
// baseline (8891.032 us; speedup 1.0000x reference)
//
#include <hip/hip_runtime.h>
#include <cmath>

#define B_ 128
#define T_ 1024
#define D_ 128
#define U_ 256
#define EPS_ 0.01f
#define GAMMA_ 0.01f

// ================= Kernel 1: h = x @ V + bias =================
// x: [B*T, D] f32, V: [D, U] f32, out: [B*T, U] f32 (h staged into d_out)
#define HG_ROWS 32

__global__ __launch_bounds__(256) void h_gemm_kernel(
    const float* __restrict__ x, const float* __restrict__ V,
    const float* __restrict__ bias, float* __restrict__ out)
{
  const int tid = threadIdx.x;                  // u = tid (0..255)
  const size_t row0 = (size_t)blockIdx.x * HG_ROWS;

  __shared__ float xs[HG_ROWS][D_];             // 16 KB
  __shared__ float vs[32][U_];                  // 32 KB

  // load x tile: 32*128 f32 = 1024 float4; 4 per thread, coalesced
  {
    const float4* xg = reinterpret_cast<const float4*>(x + row0 * D_);
    float4* xs4 = reinterpret_cast<float4*>(&xs[0][0]);
    #pragma unroll
    for (int i = 0; i < 4; ++i) xs4[i * 256 + tid] = xg[i * 256 + tid];
  }

  float acc[HG_ROWS];
  {
    float b0 = bias[tid];
    #pragma unroll
    for (int r = 0; r < HG_ROWS; ++r) acc[r] = b0;
  }

  for (int c = 0; c < 4; ++c) {
    __syncthreads();  // protect vs reuse from previous chunk
    // load V chunk rows [c*32, c*32+32): 8192 f32 = 2048 float4, 8/thread
    {
      const float4* vg = reinterpret_cast<const float4*>(V + (size_t)(c * 32) * U_);
      float4* vs4 = reinterpret_cast<float4*>(&vs[0][0]);
      #pragma unroll
      for (int i = 0; i < 8; ++i) vs4[i * 256 + tid] = vg[i * 256 + tid];
    }
    __syncthreads();

    #pragma unroll 2
    for (int d4 = 0; d4 < 8; ++d4) {
      float v0 = vs[d4 * 4 + 0][tid];   // per-lane, consecutive banks, free
      float v1 = vs[d4 * 4 + 1][tid];
      float v2 = vs[d4 * 4 + 2][tid];
      float v3 = vs[d4 * 4 + 3][tid];
      #pragma unroll
      for (int r = 0; r < HG_ROWS; ++r) {
        // wave-uniform broadcast b128 read
        float4 xr = *reinterpret_cast<const float4*>(&xs[r][c * 32 + d4 * 4]);
        acc[r] = fmaf(xr.x, v0, acc[r]);
        acc[r] = fmaf(xr.y, v1, acc[r]);
        acc[r] = fmaf(xr.z, v2, acc[r]);
        acc[r] = fmaf(xr.w, v3, acc[r]);
      }
    }
  }

  float* og = out + row0 * U_;
  #pragma unroll
  for (int r = 0; r < HG_ROWS; ++r) og[(size_t)r * U_ + tid] = acc[r];
}

// ================= Kernel 2: sequential scan over T =================
// One block per batch row. Thread (kg,u): tid = kg*256 + u.
// M column-slice kept in 64 VGPRs per thread; state in LDS.
// h was pre-staged into out[b][t][u]; overwritten in place by states.
__global__ __launch_bounds__(1024) void scan_kernel(
    const float* __restrict__ W, const float* __restrict__ x0,
    float* __restrict__ out)
{
  const int b = blockIdx.x;
  const int tid = threadIdx.x;
  const int kg = tid >> 8;      // 0..3
  const int u = tid & 255;      // 0..255

  // m[j] = M[kg*64+j][u] = W[k][u] - W[u][k] - gamma*(k==u)
  float m[64];
  {
    // W[u][k..]: per-lane contiguous 256B chunk, float4
    const float4* wt = reinterpret_cast<const float4*>(W + (size_t)u * U_ + kg * 64);
    #pragma unroll
    for (int j4 = 0; j4 < 16; ++j4) {
      float4 wu = wt[j4];
      int k = kg * 64 + j4 * 4;
      m[j4 * 4 + 0] = W[(size_t)(k + 0) * U_ + u] - wu.x;  // coalesced over u
      m[j4 * 4 + 1] = W[(size_t)(k + 1) * U_ + u] - wu.y;
      m[j4 * 4 + 2] = W[(size_t)(k + 2) * U_ + u] - wu.z;
      m[j4 * 4 + 3] = W[(size_t)(k + 3) * U_ + u] - wu.w;
    }
    if (u >= kg * 64 && u < kg * 64 + 64) m[u - kg * 64] -= GAMMA_;
  }

  __shared__ float state[U_];     // 1 KB
  __shared__ float part[4][U_];   // 4 KB

  if (tid < U_) state[tid] = x0[tid];
  __syncthreads();

  float* outb = out + (size_t)b * T_ * U_;
  float h_next = 0.0f;
  if (tid < U_) h_next = outb[u];               // prefetch h for t=0

  for (int t = 0; t < T_; ++t) {
    float h_cur = h_next;
    if (tid < U_ && t + 1 < T_) h_next = outb[(size_t)(t + 1) * U_ + u];  // issue early

    // partial dot: z_u partial over k in [kg*64, kg*64+64)
    float a0 = 0.0f, a1 = 0.0f, a2 = 0.0f, a3 = 0.0f;
    const float* sp = &state[kg * 64];
    #pragma unroll
    for (int j4 = 0; j4 < 16; ++j4) {
      float4 s4 = *reinterpret_cast<const float4*>(sp + j4 * 4);  // uniform broadcast
      a0 = fmaf(s4.x, m[j4 * 4 + 0], a0);
      a1 = fmaf(s4.y, m[j4 * 4 + 1], a1);
      a2 = fmaf(s4.z, m[j4 * 4 + 2], a2);
      a3 = fmaf(s4.w, m[j4 * 4 + 3], a3);
    }
    part[kg][u] = (a0 + a1) + (a2 + a3);
    __syncthreads();

    if (tid < U_) {
      float z = h_cur + ((part[0][u] + part[1][u]) + (part[2][u] + part[3][u]));
      float ns = state[u] + EPS_ * tanhf(z);
      state[u] = ns;
      outb[(size_t)t * U_ + u] = ns;
    }
    __syncthreads();
  }
}

extern "C" void kernel_launch(void* const* d_in, const int* in_sizes, int n_in,
                              void* d_out, int out_size, void* d_ws, size_t ws_size,
                              hipStream_t stream) {
  const float* x    = (const float*)d_in[0];  // [B,T,D]
  const float* V    = (const float*)d_in[1];  // [D,U]
  const float* W    = (const float*)d_in[2];  // [U,U]
  const float* bias = (const float*)d_in[3];  // [U]
  const float* x0   = (const float*)d_in[4];  // [U]
  float* out = (float*)d_out;                 // [B,T,U]

  // Stage h = x@V + bias into d_out, then scan overwrites it in place.
  h_gemm_kernel<<<(B_ * T_) / HG_ROWS, 256, 0, stream>>>(x, V, bias, out);
  scan_kernel<<<B_, 1024, 0, stream>>>(W, x0, out);
}

// Round 3
// 1083.161 us; speedup vs baseline: 8.2084x; 8.2084x over previous
//
#include <hip/hip_runtime.h>
#include <cmath>

#define B_ 128
#define T_ 1024
#define D_ 128
#define U_ 256
#define EPS_ 0.01f
#define GAMMA_ 0.01f

// ================= Kernel 1: h = x @ V + bias =================
// x: [B*T, D] f32, V: [D, U] f32, out: [B*T, U] f32 (h staged into d_out)
#define HG_ROWS 32

__global__ __launch_bounds__(256) void h_gemm_kernel(
    const float* __restrict__ x, const float* __restrict__ V,
    const float* __restrict__ bias, float* __restrict__ out)
{
  const int tid = threadIdx.x;                  // u = tid (0..255)
  const size_t row0 = (size_t)blockIdx.x * HG_ROWS;

  __shared__ float xs[HG_ROWS][D_];             // 16 KB
  __shared__ float vs[32][U_];                  // 32 KB

  // load x tile: 32*128 f32 = 1024 float4; 4 per thread, coalesced
  {
    const float4* xg = reinterpret_cast<const float4*>(x + row0 * D_);
    float4* xs4 = reinterpret_cast<float4*>(&xs[0][0]);
    #pragma unroll
    for (int i = 0; i < 4; ++i) xs4[i * 256 + tid] = xg[i * 256 + tid];
  }

  float acc[HG_ROWS];
  {
    float b0 = bias[tid];
    #pragma unroll
    for (int r = 0; r < HG_ROWS; ++r) acc[r] = b0;
  }

  for (int c = 0; c < 4; ++c) {
    __syncthreads();  // protect vs reuse from previous chunk
    // load V chunk rows [c*32, c*32+32): 8192 f32 = 2048 float4, 8/thread
    {
      const float4* vg = reinterpret_cast<const float4*>(V + (size_t)(c * 32) * U_);
      float4* vs4 = reinterpret_cast<float4*>(&vs[0][0]);
      #pragma unroll
      for (int i = 0; i < 8; ++i) vs4[i * 256 + tid] = vg[i * 256 + tid];
    }
    __syncthreads();

    #pragma unroll 2
    for (int d4 = 0; d4 < 8; ++d4) {
      float v0 = vs[d4 * 4 + 0][tid];   // per-lane, consecutive banks, free
      float v1 = vs[d4 * 4 + 1][tid];
      float v2 = vs[d4 * 4 + 2][tid];
      float v3 = vs[d4 * 4 + 3][tid];
      #pragma unroll
      for (int r = 0; r < HG_ROWS; ++r) {
        // wave-uniform broadcast b128 read
        float4 xr = *reinterpret_cast<const float4*>(&xs[r][c * 32 + d4 * 4]);
        acc[r] = fmaf(xr.x, v0, acc[r]);
        acc[r] = fmaf(xr.y, v1, acc[r]);
        acc[r] = fmaf(xr.z, v2, acc[r]);
        acc[r] = fmaf(xr.w, v3, acc[r]);
      }
    }
  }

  float* og = out + row0 * U_;
  #pragma unroll
  for (int r = 0; r < HG_ROWS; ++r) og[(size_t)r * U_ + tid] = acc[r];
}

// ================= Kernel 2: sequential scan over T =================
// One block per batch row. Thread (kg,u): tid = kg*256 + u.
// M column-slice kept in 64 VGPRs per thread (ALL indices compile-time
// constant — any runtime index demotes the array to scratch, rule #20).
// State in LDS; h pre-staged in out[b][t][u], overwritten in place.
__global__ __launch_bounds__(1024) void scan_kernel(
    const float* __restrict__ W, const float* __restrict__ x0,
    float* __restrict__ out)
{
  const int b = blockIdx.x;
  const int tid = threadIdx.x;
  const int kg = tid >> 8;      // 0..3
  const int u = tid & 255;      // 0..255

  // m[j] = M[kg*64+j][u] = W[k][u] - W[u][k] - gamma*(k==u)
  float m[64];
  {
    // W[u][k..]: per-lane contiguous 256B chunk, float4
    const float4* wt = reinterpret_cast<const float4*>(W + (size_t)u * U_ + kg * 64);
    #pragma unroll
    for (int j4 = 0; j4 < 16; ++j4) {
      float4 wu = wt[j4];
      const int k = kg * 64 + j4 * 4;
      // gamma folded in with compile-time m[] indices (no runtime indexing!)
      m[j4 * 4 + 0] = W[(size_t)(k + 0) * U_ + u] - wu.x - ((k + 0) == u ? GAMMA_ : 0.0f);
      m[j4 * 4 + 1] = W[(size_t)(k + 1) * U_ + u] - wu.y - ((k + 1) == u ? GAMMA_ : 0.0f);
      m[j4 * 4 + 2] = W[(size_t)(k + 2) * U_ + u] - wu.z - ((k + 2) == u ? GAMMA_ : 0.0f);
      m[j4 * 4 + 3] = W[(size_t)(k + 3) * U_ + u] - wu.w - ((k + 3) == u ? GAMMA_ : 0.0f);
    }
  }

  __shared__ float state[U_];     // 1 KB
  __shared__ float part[4][U_];   // 4 KB

  if (tid < U_) state[tid] = x0[tid];
  __syncthreads();

  float* outb = out + (size_t)b * T_ * U_;
  float h_next = 0.0f;
  if (tid < U_) h_next = outb[u];               // prefetch h for t=0

  for (int t = 0; t < T_; ++t) {
    float h_cur = h_next;
    if (tid < U_ && t + 1 < T_) h_next = outb[(size_t)(t + 1) * U_ + u];  // issue early

    // partial dot: z_u partial over k in [kg*64, kg*64+64)
    float a0 = 0.0f, a1 = 0.0f, a2 = 0.0f, a3 = 0.0f;
    const float* sp = &state[kg * 64];
    #pragma unroll
    for (int j4 = 0; j4 < 16; ++j4) {
      float4 s4 = *reinterpret_cast<const float4*>(sp + j4 * 4);  // uniform broadcast
      a0 = fmaf(s4.x, m[j4 * 4 + 0], a0);
      a1 = fmaf(s4.y, m[j4 * 4 + 1], a1);
      a2 = fmaf(s4.z, m[j4 * 4 + 2], a2);
      a3 = fmaf(s4.w, m[j4 * 4 + 3], a3);
    }
    part[kg][u] = (a0 + a1) + (a2 + a3);
    __syncthreads();

    if (tid < U_) {
      float z = h_cur + ((part[0][u] + part[1][u]) + (part[2][u] + part[3][u]));
      // fast tanh: 1 - 2/(e^{2z}+1); |z| small here, err ~1e-7
      float e = __expf(2.0f * z);
      float th = 1.0f - 2.0f * __builtin_amdgcn_rcpf(e + 1.0f);
      float ns = state[u] + EPS_ * th;
      state[u] = ns;
      outb[(size_t)t * U_ + u] = ns;
    }
    __syncthreads();
  }
}

extern "C" void kernel_launch(void* const* d_in, const int* in_sizes, int n_in,
                              void* d_out, int out_size, void* d_ws, size_t ws_size,
                              hipStream_t stream) {
  const float* x    = (const float*)d_in[0];  // [B,T,D]
  const float* V    = (const float*)d_in[1];  // [D,U]
  const float* W    = (const float*)d_in[2];  // [U,U]
  const float* bias = (const float*)d_in[3];  // [U]
  const float* x0   = (const float*)d_in[4];  // [U]
  float* out = (float*)d_out;                 // [B,T,U]

  // Stage h = x@V + bias into d_out, then scan overwrites it in place.
  h_gemm_kernel<<<(B_ * T_) / HG_ROWS, 256, 0, stream>>>(x, V, bias, out);
  scan_kernel<<<B_, 1024, 0, stream>>>(W, x0, out);
}